// Round 4
// baseline (185.629 us; speedup 1.0000x reference)
//
#include <hip/hip_runtime.h>

#define BN 1024
#define NV 6890
#define NBETA 10
#define PB 207            // pose basis = 9*(J-1)
#define N3 20670          // NV*3
#define NCOL 20736        // 108*192 padded GEMM columns
#define NCHUNK 7          // K = 224 = 207 pose + 10 betas + 1 template + 6 zero
#define BT 32             // batches per k_vert block

typedef __bf16 bf16x8 __attribute__((ext_vector_type(8)));
typedef float  f32x4  __attribute__((ext_vector_type(4)));

__device__ __constant__ int c_par[24] = {-1,0,0,0,1,2,3,4,5,6,7,8,9,9,9,12,13,14,16,17,18,19,20,21};

__device__ inline unsigned short f2bf(float f) {
    unsigned u = __float_as_uint(f);
    u += 0x7fff + ((u >> 16) & 1);          // RNE
    return (unsigned short)(u >> 16);
}

// ---------------------------------------------------------------------------
// k_prep: one kernel, 4 disjoint block ranges.
//  A [0,567):      pd repack -> ws_pdt[kc][col][40] bf16 (pose;shape;template)
//  B [567,799):    pose_feature+betas+1 -> ws_pfb[b][232] bf16
//  C [799,1069):   lbs weights -> ws_wb[v][40] bf16 (v<6912)
//  D [1069,1645):  J_regressor partial reductions -> ws_jsp (8 seg x 72 x 11)
// ---------------------------------------------------------------------------
__global__ __launch_bounds__(256) void k_prep(const float* __restrict__ pd,
                                              const float* __restrict__ sd,
                                              const float* __restrict__ vtm,
                                              const float* __restrict__ Jr,
                                              const float* __restrict__ bpose,
                                              const float* __restrict__ betas,
                                              const float* __restrict__ w,
                                              unsigned short* __restrict__ ws_pdt,
                                              unsigned short* __restrict__ ws_pfb,
                                              unsigned short* __restrict__ ws_wb,
                                              float* __restrict__ ws_jsp)
{
    int blk = blockIdx.x;
    if (blk < 567) {
        int t = blk * 256 + threadIdx.x;           // 0..145151
        int kc = t / NCOL;
        int col = t - kc * NCOL;
        bool cok = col < N3;
        unsigned short vals[40];
        #pragma unroll
        for (int kk = 0; kk < 32; kk++) {
            int gk = kc * 32 + kk;
            float val = 0.f;
            if (cok) {
                if (gk < PB)             val = pd[(size_t)gk * N3 + col];
                else if (gk < PB + 10)   val = sd[(size_t)col * NBETA + (gk - PB)];
                else if (gk == PB + 10)  val = vtm[col];
            }
            vals[kk] = f2bf(val);
        }
        #pragma unroll
        for (int kk = 32; kk < 40; kk++) vals[kk] = 0;
        uint4* dst = (uint4*)(ws_pdt + (size_t)t * 40);
        #pragma unroll
        for (int q = 0; q < 5; q++) {
            uint4 u;
            u.x = vals[q*8+0] | ((unsigned)vals[q*8+1] << 16);
            u.y = vals[q*8+2] | ((unsigned)vals[q*8+3] << 16);
            u.z = vals[q*8+4] | ((unsigned)vals[q*8+5] << 16);
            u.w = vals[q*8+6] | ((unsigned)vals[q*8+7] << 16);
            dst[q] = u;
        }
    } else if (blk < 799) {
        int e0 = (blk - 567) * 1024 + threadIdx.x * 4;   // 232*1024 total
        unsigned short v4[4];
        #pragma unroll
        for (int r = 0; r < 4; r++) {
            int e = e0 + r;
            int b = e / 232, k = e - b * 232;
            float x = 0.f;
            if (k < PB) {
                x = bpose[(size_t)b * PB + k];
                int k9 = k % 9;
                if (k9 == 0 || k9 == 4 || k9 == 8) x -= 1.f;
            } else if (k < PB + 10) {
                x = betas[b * NBETA + (k - PB)];
            } else if (k == PB + 10) {
                x = 1.f;
            }
            v4[r] = f2bf(x);
        }
        uint2 u;
        u.x = v4[0] | ((unsigned)v4[1] << 16);
        u.y = v4[2] | ((unsigned)v4[3] << 16);
        *(uint2*)(ws_pfb + e0) = u;
    } else if (blk < 1069) {
        int e0 = (blk - 799) * 1024 + threadIdx.x * 4;   // 6912*40 total
        unsigned short v4[4];
        #pragma unroll
        for (int r = 0; r < 4; r++) {
            int e = e0 + r;
            int v = e / 40, j = e - v * 40;
            float val = (j < 24 && v < NV) ? w[(size_t)v * 24 + j] : 0.f;
            v4[r] = f2bf(val);
        }
        uint2 u;
        u.x = v4[0] | ((unsigned)v4[1] << 16);
        u.y = v4[2] | ((unsigned)v4[3] << 16);
        *(uint2*)(ws_wb + e0) = u;
    } else {
        int b2 = blk - 1069;           // 0..575
        int jc = b2 >> 3;              // 0..71
        int seg = b2 & 7;              // 0..7
        int j = jc / 3, c = jc % 3;
        int v0 = seg * 862;
        int v1 = v0 + 862; if (v1 > NV) v1 = NV;

        float acc[11];
        #pragma unroll
        for (int l = 0; l < 11; l++) acc[l] = 0.f;

        for (int v = v0 + threadIdx.x; v < v1; v += 256) {
            float r = Jr[j * NV + v];
            acc[10] += r * vtm[v * 3 + c];
            const float* s = sd + (size_t)(v * 3 + c) * NBETA;
            #pragma unroll
            for (int l = 0; l < NBETA; l++) acc[l] += r * s[l];
        }

        __shared__ float red[4][11];
        int lane = threadIdx.x & 63, wv = threadIdx.x >> 6;
        #pragma unroll
        for (int l = 0; l < 11; l++) {
            float x = acc[l];
            x += __shfl_down(x, 32, 64);
            x += __shfl_down(x, 16, 64);
            x += __shfl_down(x, 8, 64);
            x += __shfl_down(x, 4, 64);
            x += __shfl_down(x, 2, 64);
            x += __shfl_down(x, 1, 64);
            if (lane == 0) red[wv][l] = x;
        }
        __syncthreads();
        if (threadIdx.x == 0) {
            #pragma unroll
            for (int l = 0; l < 11; l++)
                ws_jsp[((size_t)seg * 72 + jc) * 11 + l]
                    = red[0][l] + red[1][l] + red[2][l] + red[3][l];
        }
    }
}

// ---------------------------------------------------------------------------
// k_chain: 64 blocks x 256 threads, 16 batches/block (16 lanes per batch).
// Sums js partials, joints + kinematic chain; emits bf16 ArT[b][12][40] + pj.
// ---------------------------------------------------------------------------
__global__ __launch_bounds__(256) void k_chain(const float* __restrict__ betas,
                                               const float* __restrict__ grot,
                                               const float* __restrict__ bpose,
                                               const float* __restrict__ ws_jsp,
                                               unsigned short* __restrict__ ws_artb,
                                               float* __restrict__ pj)
{
    __shared__ float js_s[72 * 11];
    __shared__ float jt[16][72];
    __shared__ float tl[16][288];
    __shared__ float am[16][288];
    int tid = threadIdx.x;

    for (int e = tid; e < 72 * 11; e += 256) {
        float s = 0.f;
        #pragma unroll
        for (int seg = 0; seg < 8; seg++)
            s += ws_jsp[(size_t)seg * 792 + e];
        js_s[e] = s;
    }
    __syncthreads();

    int lb = tid >> 4;              // 0..15
    int e  = tid & 15;              // 0..15
    int b  = blockIdx.x * 16 + lb;

    for (int idx = e; idx < 72; idx += 16) {
        float acc = js_s[idx * 11 + 10];
        const float* be = betas + b * NBETA;
        #pragma unroll
        for (int l = 0; l < NBETA; l++) acc += be[l] * js_s[idx * 11 + l];
        jt[lb][idx] = acc;
    }
    __syncthreads();

    for (int idx = e; idx < 288; idx += 16) {
        int j = idx / 12, e12 = idx % 12, m = e12 >> 2, n = e12 & 3;
        float val;
        if (n < 3) {
            val = (j == 0) ? grot[(size_t)b * 9 + m * 3 + n]
                           : bpose[((size_t)b * 23 + (j - 1)) * 9 + m * 3 + n];
        } else {
            val = jt[lb][j * 3 + m];
            if (j > 0) val -= jt[lb][c_par[j] * 3 + m];
        }
        tl[lb][idx] = val;
    }
    __syncthreads();

    if (e < 12) am[lb][e] = tl[lb][e];
    for (int i = 1; i < 24; i++) {
        __syncthreads();
        if (e < 12) {
            int p = c_par[i];
            int m = e >> 2, n = e & 3;
            float val = am[lb][p*12 + m*4 + 0] * tl[lb][i*12 + 0 + n]
                      + am[lb][p*12 + m*4 + 1] * tl[lb][i*12 + 4 + n]
                      + am[lb][p*12 + m*4 + 2] * tl[lb][i*12 + 8 + n];
            if (n == 3) val += am[lb][p*12 + m*4 + 3];
            am[lb][i*12 + e] = val;
        }
    }
    __syncthreads();

    for (int idx = e; idx < 72; idx += 16) {
        int j = idx / 3, m = idx % 3;
        pj[(size_t)b * 72 + idx] = am[lb][j*12 + m*4 + 3];
    }
    // ArT[b][col=m*4+n][j'] bf16, j' 0..39 (24..39 zero)
    for (int idx = e; idx < 480; idx += 16) {
        int col = idx / 40, j = idx - col * 40;
        float val = 0.f;
        if (j < 24) {
            int m = col >> 2, n = col & 3;
            if (n < 3) {
                val = am[lb][j*12 + col];
            } else {
                val = am[lb][j*12 + m*4 + 3]
                    - am[lb][j*12 + m*4 + 0] * jt[lb][j*3 + 0]
                    - am[lb][j*12 + m*4 + 1] * jt[lb][j*3 + 1]
                    - am[lb][j*12 + m*4 + 2] * jt[lb][j*3 + 2];
            }
        }
        ws_artb[(size_t)b * 480 + idx] = f2bf(val);
    }
}

// ---------------------------------------------------------------------------
// k_vert: direct global->register MFMA operands, one barrier total.
// This round:
//  (1) XCD-partition swizzle: each XCD owns a contiguous vb range, so its
//      2.5 MB working set (pdt slices + artb + wb) stays L2-resident ->
//      operand loads become L2 hits instead of L3/HBM misses.
//  (2) __launch_bounds__(256,6): 6 blocks/CU (24 waves) for latency hiding.
//      LDS 6*25088 = 150.5 KB <= 160 KB; VGPR cap 85 >> 40 used.
// ---------------------------------------------------------------------------
__global__ __launch_bounds__(256, 6) void k_vert(const unsigned short* __restrict__ ws_pdt,
                                                 const unsigned short* __restrict__ ws_pfb,
                                                 const unsigned short* __restrict__ ws_wb,
                                                 const unsigned short* __restrict__ ws_artb,
                                                 float* __restrict__ out)
{
    // XCD-partition swizzle (bijective on [0,3456)): lin%8 = XCD id.
    // Each XCD gets g in [xcd*432, (xcd+1)*432) = 13.5 vb-slices x 32 bb.
    const int lin = blockIdx.x + 32 * blockIdx.y;   // 0..3455
    const int xcd = lin & 7;
    const int loc = lin >> 3;                        // 0..431
    const int g_id = xcd * 432 + loc;
    const int bb = g_id & 31;                        // 0..31
    const int vb = g_id >> 5;                        // 0..107

    const int tid = threadIdx.x;
    const int wv = tid >> 6;
    const int lane = tid & 63;
    const int r16 = lane & 15;
    const int half8 = (lane >> 4) * 8;

    __shared__ __align__(16) float disp_l[32 * 196];   // 25,088 B

    // ---- phase 1: v_posed GEMM, direct-global fragments, depth-1 pipeline
    const unsigned short* pfbase = ws_pfb + (size_t)(bb * BT) * 232;
    const unsigned short* pB0 = ws_pdt + ((size_t)vb * 192 + wv * 48 + r16) * 40 + half8;

    bf16x8 a0 = *(const bf16x8*)(pfbase + r16 * 232 + half8);
    bf16x8 a1 = *(const bf16x8*)(pfbase + (16 + r16) * 232 + half8);
    bf16x8 b0 = *(const bf16x8*)(pB0);
    bf16x8 b1 = *(const bf16x8*)(pB0 + 640);    // +16 rows * 40
    bf16x8 b2 = *(const bf16x8*)(pB0 + 1280);   // +32 rows * 40

    f32x4 acc[2][3];
    #pragma unroll
    for (int mt = 0; mt < 2; mt++)
        #pragma unroll
        for (int t = 0; t < 3; t++)
            acc[mt][t] = (f32x4){0.f, 0.f, 0.f, 0.f};

    #pragma unroll
    for (int kc = 0; kc < NCHUNK; kc++) {
        bf16x8 a0n, a1n, b0n, b1n, b2n;
        if (kc < NCHUNK - 1) {
            const unsigned short* pn = pB0 + (size_t)(kc + 1) * NCOL * 40;
            b0n = *(const bf16x8*)(pn);
            b1n = *(const bf16x8*)(pn + 640);
            b2n = *(const bf16x8*)(pn + 1280);
            a0n = *(const bf16x8*)(pfbase + r16 * 232 + (kc + 1) * 32 + half8);
            a1n = *(const bf16x8*)(pfbase + (16 + r16) * 232 + (kc + 1) * 32 + half8);
        }
        acc[0][0] = __builtin_amdgcn_mfma_f32_16x16x32_bf16(a0, b0, acc[0][0], 0, 0, 0);
        acc[1][0] = __builtin_amdgcn_mfma_f32_16x16x32_bf16(a1, b0, acc[1][0], 0, 0, 0);
        acc[0][1] = __builtin_amdgcn_mfma_f32_16x16x32_bf16(a0, b1, acc[0][1], 0, 0, 0);
        acc[1][1] = __builtin_amdgcn_mfma_f32_16x16x32_bf16(a1, b1, acc[1][1], 0, 0, 0);
        acc[0][2] = __builtin_amdgcn_mfma_f32_16x16x32_bf16(a0, b2, acc[0][2], 0, 0, 0);
        acc[1][2] = __builtin_amdgcn_mfma_f32_16x16x32_bf16(a1, b2, acc[1][2], 0, 0, 0);
        if (kc < NCHUNK - 1) { a0 = a0n; a1 = a1n; b0 = b0n; b1 = b1n; b2 = b2n; }
    }

    // ---- scatter v_posed into disp_l
    // stride 196: lane-groups land at bank offsets {0,16,0,16} -> 2-way (free)
    #pragma unroll
    for (int mt = 0; mt < 2; mt++) {
        #pragma unroll
        for (int t = 0; t < 3; t++) {
            int col = wv * 48 + t * 16 + r16;
            int brow = mt * 16 + (lane >> 4) * 4;
            #pragma unroll
            for (int r = 0; r < 4; r++)
                disp_l[(brow + r) * 196 + col] = acc[mt][t][r];
        }
    }
    __syncthreads();     // the kernel's only barrier

    // ---- phase 2: T = w @ ArT with swapped operands, direct-global frags
    bf16x8 aw = *(const bf16x8*)(ws_wb + (size_t)(vb * 64 + wv * 16 + r16) * 40 + half8);

    const int gq = lane >> 4;
    const int v16 = wv * 16 + r16;            // vert within block (C col)
    const int vg = vb * 64 + v16;             // global vert
    // Per tile t: artcol = 16t + 4g + r -> q = 4t+g (lane-const), n = r (reg).
    int bl[3], mm[3];
    #pragma unroll
    for (int t = 0; t < 3; t++) {
        int q = 4 * t + gq;                   // 0..11
        bl[t] = (q * 11) >> 5;                // q/3 for q in [0,12)
        mm[t] = q - 3 * bl[t];
    }

    // ws_artb view: [batch][12 artcols][40]; frag row (per sub s, tile t):
    // global addr = base + sub*4*480 + (t*16 + r16)*40 + half8
    const unsigned short* pArt = ws_artb + (size_t)(bb * BT) * 480 + (size_t)r16 * 40 + half8;

    bf16x8 c0 = *(const bf16x8*)(pArt);
    bf16x8 c1 = *(const bf16x8*)(pArt + 640);
    bf16x8 c2 = *(const bf16x8*)(pArt + 1280);

    #pragma unroll
    for (int sub = 0; sub < 8; sub++) {
        bf16x8 c0n, c1n, c2n;
        if (sub < 7) {
            const unsigned short* pn = pArt + (size_t)(sub + 1) * 1920;  // 4 batches * 480
            c0n = *(const bf16x8*)(pn);
            c1n = *(const bf16x8*)(pn + 640);
            c2n = *(const bf16x8*)(pn + 1280);
        }
        f32x4 z = (f32x4){0.f, 0.f, 0.f, 0.f};
        // swapped operands: C[artcol][vert]
        f32x4 t0 = __builtin_amdgcn_mfma_f32_16x16x32_bf16(c0, aw, z, 0, 0, 0);
        f32x4 t1 = __builtin_amdgcn_mfma_f32_16x16x32_bf16(c1, aw, z, 0, 0, 0);
        f32x4 t2 = __builtin_amdgcn_mfma_f32_16x16x32_bf16(c2, aw, z, 0, 0, 0);

        #pragma unroll
        for (int t = 0; t < 3; t++) {
            f32x4 tt = (t == 0) ? t0 : (t == 1) ? t1 : t2;
            int row = sub * 4 + bl[t];
            const float* d = disp_l + row * 196 + v16 * 3;
            float x = d[0], y = d[1], zz = d[2];
            float p = tt[0] * x + tt[1] * y + tt[2] * zz + tt[3];
            if (vg < NV)
                out[(size_t)(bb * BT + row) * N3 + (size_t)vg * 3 + mm[t]] = p;
        }
        if (sub < 7) { c0 = c0n; c1 = c1n; c2 = c2n; }
    }
}

// ---------------------------------------------------------------------------
extern "C" void kernel_launch(void* const* d_in, const int* in_sizes, int n_in,
                              void* d_out, int out_size, void* d_ws, size_t ws_size,
                              hipStream_t stream) {
    const float* betas = (const float*)d_in[0];
    const float* grot  = (const float*)d_in[1];
    const float* bpose = (const float*)d_in[2];
    const float* vtm   = (const float*)d_in[3];
    const float* sd    = (const float*)d_in[4];
    const float* pd    = (const float*)d_in[5];
    const float* Jr    = (const float*)d_in[6];
    const float* w     = (const float*)d_in[7];
    float* out = (float*)d_out;

    char* ws = (char*)d_ws;
    unsigned short* ws_pdt  = (unsigned short*)(ws);              // 11,612,160 B
    unsigned short* ws_pfb  = (unsigned short*)(ws + 11612160);   //    475,136 B
    unsigned short* ws_wb   = (unsigned short*)(ws + 12087296);   //    552,960 B
    float*          ws_jsp  = (float*)         (ws + 12640256);   //     25,344 B
    unsigned short* ws_artb = (unsigned short*)(ws + 12665600);   //    983,040 B

    k_prep<<<1645, 256, 0, stream>>>(pd, sd, vtm, Jr, bpose, betas, w,
                                     ws_pdt, ws_pfb, ws_wb, ws_jsp);
    k_chain<<<BN / 16, 256, 0, stream>>>(betas, grot, bpose, ws_jsp, ws_artb,
                                         out + (size_t)BN * N3);
    k_vert<<<dim3(32, 108), 256, 0, stream>>>(ws_pdt, ws_pfb, ws_wb, ws_artb, out);
}

// Round 6
// 171.144 us; speedup vs baseline: 1.0846x; 1.0846x over previous
//
#include <hip/hip_runtime.h>

#define BN 1024
#define NV 6890
#define NBETA 10
#define PB 207            // pose basis = 9*(J-1)
#define N3 20670          // NV*3
#define NCOL 20736        // 108*192 padded GEMM columns
#define NCHUNK 7          // K = 224 = 207 pose + 10 betas + 1 template + 6 zero
#define BT 32             // batches per k_vert block

typedef __bf16 bf16x8 __attribute__((ext_vector_type(8)));
typedef float  f32x4  __attribute__((ext_vector_type(4)));

__device__ __constant__ int c_par[24] = {-1,0,0,0,1,2,3,4,5,6,7,8,9,9,9,12,13,14,16,17,18,19,20,21};

__device__ inline unsigned short f2bf(float f) {
    unsigned u = __float_as_uint(f);
    u += 0x7fff + ((u >> 16) & 1);          // RNE
    return (unsigned short)(u >> 16);
}

__device__ inline void dma16(const void* g, void* l) {
    __builtin_amdgcn_global_load_lds(
        (const __attribute__((address_space(1))) unsigned int*)g,
        (__attribute__((address_space(3))) unsigned int*)l, 16, 0, 0);
}

// ---------------------------------------------------------------------------
// k_prep: one kernel, 4 disjoint block ranges.
//  A [0,567):      pd repack -> ws_pdt[kc][col][40] bf16 (pose;shape;template)
//  B [567,799):    pose_feature+betas+1 -> ws_pfb[b][232] bf16
//  C [799,1069):   lbs weights -> ws_wb[v][40] bf16 (v<6912)
//  D [1069,1645):  J_regressor partial reductions -> ws_jsp (8 seg x 72 x 11)
// ---------------------------------------------------------------------------
__global__ __launch_bounds__(256) void k_prep(const float* __restrict__ pd,
                                              const float* __restrict__ sd,
                                              const float* __restrict__ vtm,
                                              const float* __restrict__ Jr,
                                              const float* __restrict__ bpose,
                                              const float* __restrict__ betas,
                                              const float* __restrict__ w,
                                              unsigned short* __restrict__ ws_pdt,
                                              unsigned short* __restrict__ ws_pfb,
                                              unsigned short* __restrict__ ws_wb,
                                              float* __restrict__ ws_jsp)
{
    int blk = blockIdx.x;
    if (blk < 567) {
        int t = blk * 256 + threadIdx.x;           // 0..145151
        int kc = t / NCOL;
        int col = t - kc * NCOL;
        bool cok = col < N3;
        unsigned short vals[40];
        #pragma unroll
        for (int kk = 0; kk < 32; kk++) {
            int gk = kc * 32 + kk;
            float val = 0.f;
            if (cok) {
                if (gk < PB)             val = pd[(size_t)gk * N3 + col];
                else if (gk < PB + 10)   val = sd[(size_t)col * NBETA + (gk - PB)];
                else if (gk == PB + 10)  val = vtm[col];
            }
            vals[kk] = f2bf(val);
        }
        #pragma unroll
        for (int kk = 32; kk < 40; kk++) vals[kk] = 0;
        uint4* dst = (uint4*)(ws_pdt + (size_t)t * 40);
        #pragma unroll
        for (int q = 0; q < 5; q++) {
            uint4 u;
            u.x = vals[q*8+0] | ((unsigned)vals[q*8+1] << 16);
            u.y = vals[q*8+2] | ((unsigned)vals[q*8+3] << 16);
            u.z = vals[q*8+4] | ((unsigned)vals[q*8+5] << 16);
            u.w = vals[q*8+6] | ((unsigned)vals[q*8+7] << 16);
            dst[q] = u;
        }
    } else if (blk < 799) {
        int e0 = (blk - 567) * 1024 + threadIdx.x * 4;   // 232*1024 total
        unsigned short v4[4];
        #pragma unroll
        for (int r = 0; r < 4; r++) {
            int e = e0 + r;
            int b = e / 232, k = e - b * 232;
            float x = 0.f;
            if (k < PB) {
                x = bpose[(size_t)b * PB + k];
                int k9 = k % 9;
                if (k9 == 0 || k9 == 4 || k9 == 8) x -= 1.f;
            } else if (k < PB + 10) {
                x = betas[b * NBETA + (k - PB)];
            } else if (k == PB + 10) {
                x = 1.f;
            }
            v4[r] = f2bf(x);
        }
        uint2 u;
        u.x = v4[0] | ((unsigned)v4[1] << 16);
        u.y = v4[2] | ((unsigned)v4[3] << 16);
        *(uint2*)(ws_pfb + e0) = u;
    } else if (blk < 1069) {
        int e0 = (blk - 799) * 1024 + threadIdx.x * 4;   // 6912*40 total
        unsigned short v4[4];
        #pragma unroll
        for (int r = 0; r < 4; r++) {
            int e = e0 + r;
            int v = e / 40, j = e - v * 40;
            float val = (j < 24 && v < NV) ? w[(size_t)v * 24 + j] : 0.f;
            v4[r] = f2bf(val);
        }
        uint2 u;
        u.x = v4[0] | ((unsigned)v4[1] << 16);
        u.y = v4[2] | ((unsigned)v4[3] << 16);
        *(uint2*)(ws_wb + e0) = u;
    } else {
        int b2 = blk - 1069;           // 0..575
        int jc = b2 >> 3;              // 0..71
        int seg = b2 & 7;              // 0..7
        int j = jc / 3, c = jc % 3;
        int v0 = seg * 862;
        int v1 = v0 + 862; if (v1 > NV) v1 = NV;

        float acc[11];
        #pragma unroll
        for (int l = 0; l < 11; l++) acc[l] = 0.f;

        for (int v = v0 + threadIdx.x; v < v1; v += 256) {
            float r = Jr[j * NV + v];
            acc[10] += r * vtm[v * 3 + c];
            const float* s = sd + (size_t)(v * 3 + c) * NBETA;
            #pragma unroll
            for (int l = 0; l < NBETA; l++) acc[l] += r * s[l];
        }

        __shared__ float red[4][11];
        int lane = threadIdx.x & 63, wv = threadIdx.x >> 6;
        #pragma unroll
        for (int l = 0; l < 11; l++) {
            float x = acc[l];
            x += __shfl_down(x, 32, 64);
            x += __shfl_down(x, 16, 64);
            x += __shfl_down(x, 8, 64);
            x += __shfl_down(x, 4, 64);
            x += __shfl_down(x, 2, 64);
            x += __shfl_down(x, 1, 64);
            if (lane == 0) red[wv][l] = x;
        }
        __syncthreads();
        if (threadIdx.x == 0) {
            #pragma unroll
            for (int l = 0; l < 11; l++)
                ws_jsp[((size_t)seg * 72 + jc) * 11 + l]
                    = red[0][l] + red[1][l] + red[2][l] + red[3][l];
        }
    }
}

// ---------------------------------------------------------------------------
// k_chain: 64 blocks x 256 threads, 16 batches/block (16 lanes per batch).
// Sums js partials, joints + kinematic chain; emits bf16 ArT[b][12][40] + pj.
// ---------------------------------------------------------------------------
__global__ __launch_bounds__(256) void k_chain(const float* __restrict__ betas,
                                               const float* __restrict__ grot,
                                               const float* __restrict__ bpose,
                                               const float* __restrict__ ws_jsp,
                                               unsigned short* __restrict__ ws_artb,
                                               float* __restrict__ pj)
{
    __shared__ float js_s[72 * 11];
    __shared__ float jt[16][72];
    __shared__ float tl[16][288];
    __shared__ float am[16][288];
    int tid = threadIdx.x;

    for (int e = tid; e < 72 * 11; e += 256) {
        float s = 0.f;
        #pragma unroll
        for (int seg = 0; seg < 8; seg++)
            s += ws_jsp[(size_t)seg * 792 + e];
        js_s[e] = s;
    }
    __syncthreads();

    int lb = tid >> 4;              // 0..15
    int e  = tid & 15;              // 0..15
    int b  = blockIdx.x * 16 + lb;

    for (int idx = e; idx < 72; idx += 16) {
        float acc = js_s[idx * 11 + 10];
        const float* be = betas + b * NBETA;
        #pragma unroll
        for (int l = 0; l < NBETA; l++) acc += be[l] * js_s[idx * 11 + l];
        jt[lb][idx] = acc;
    }
    __syncthreads();

    for (int idx = e; idx < 288; idx += 16) {
        int j = idx / 12, e12 = idx % 12, m = e12 >> 2, n = e12 & 3;
        float val;
        if (n < 3) {
            val = (j == 0) ? grot[(size_t)b * 9 + m * 3 + n]
                           : bpose[((size_t)b * 23 + (j - 1)) * 9 + m * 3 + n];
        } else {
            val = jt[lb][j * 3 + m];
            if (j > 0) val -= jt[lb][c_par[j] * 3 + m];
        }
        tl[lb][idx] = val;
    }
    __syncthreads();

    if (e < 12) am[lb][e] = tl[lb][e];
    for (int i = 1; i < 24; i++) {
        __syncthreads();
        if (e < 12) {
            int p = c_par[i];
            int m = e >> 2, n = e & 3;
            float val = am[lb][p*12 + m*4 + 0] * tl[lb][i*12 + 0 + n]
                      + am[lb][p*12 + m*4 + 1] * tl[lb][i*12 + 4 + n]
                      + am[lb][p*12 + m*4 + 2] * tl[lb][i*12 + 8 + n];
            if (n == 3) val += am[lb][p*12 + m*4 + 3];
            am[lb][i*12 + e] = val;
        }
    }
    __syncthreads();

    for (int idx = e; idx < 72; idx += 16) {
        int j = idx / 3, m = idx % 3;
        pj[(size_t)b * 72 + idx] = am[lb][j*12 + m*4 + 3];
    }
    // ArT[b][col=m*4+n][j'] bf16, j' 0..39 (24..39 zero)
    for (int idx = e; idx < 480; idx += 16) {
        int col = idx / 40, j = idx - col * 40;
        float val = 0.f;
        if (j < 24) {
            int m = col >> 2, n = col & 3;
            if (n < 3) {
                val = am[lb][j*12 + col];
            } else {
                val = am[lb][j*12 + m*4 + 3]
                    - am[lb][j*12 + m*4 + 0] * jt[lb][j*3 + 0]
                    - am[lb][j*12 + m*4 + 1] * jt[lb][j*3 + 1]
                    - am[lb][j*12 + m*4 + 2] * jt[lb][j*3 + 2];
            }
        }
        ws_artb[(size_t)b * 480 + idx] = f2bf(val);
    }
}

// ---------------------------------------------------------------------------
// k_vert, round 5 resubmit (r5 bench was an infra failure, kernel never ran).
// Theory: vmem-throughput bound; cut redundant vmem traffic.
//  (1) pfb slice (14.8 KB, identical across all 4 waves) staged in LDS via
//      DMA once per block; a-frags via ds_read_b128. -14 vmem instr/wave.
//  (2) phase 2 re-mapped: wave wv owns subs {wv, wv+4} x ALL 4 vert-groups
//      (aw[4] in regs). c-loads 24 -> 6 per wave. -15 vmem instr/wave.
//  Per-wave vmem instrs 84 -> 55; global load traffic ~660 -> ~290 MB.
//  LDS: disp 25,088 + pfb 15,360 = 40,448 B -> 4 blocks/CU. 2 barriers.
//  XCD-partition swizzle kept (FETCH 48->13 MB in r4).
// ---------------------------------------------------------------------------
__global__ __launch_bounds__(256, 4) void k_vert(const unsigned short* __restrict__ ws_pdt,
                                                 const unsigned short* __restrict__ ws_pfb,
                                                 const unsigned short* __restrict__ ws_wb,
                                                 const unsigned short* __restrict__ ws_artb,
                                                 float* __restrict__ out)
{
    // XCD-partition swizzle (bijective on [0,3456)): lin%8 = XCD id.
    const int lin = blockIdx.x + 32 * blockIdx.y;   // 0..3455
    const int xcd = lin & 7;
    const int loc = lin >> 3;                        // 0..431
    const int g_id = xcd * 432 + loc;
    const int bb = g_id & 31;                        // 0..31
    const int vb = g_id >> 5;                        // 0..107

    const int tid = threadIdx.x;
    const int wv = tid >> 6;
    const int lane = tid & 63;
    const int r16 = lane & 15;
    const int half8 = (lane >> 4) * 8;

    __shared__ __align__(16) unsigned char smem[40448];
    float*          disp_l = (float*)smem;                    // [32][196] = 25,088 B
    unsigned short* pfb_l  = (unsigned short*)(smem + 25088); // 15,360 B (14,848 used)

    // ---- DMA pfb slice for bb into LDS. 14 full 1-KB chunks + a clamped
    // tail chunk (512 B) so the global read never leaves ws_pfb's 14,848-B
    // row block. LDS bytes beyond 14,848 are never read.
    {
        const unsigned short* srcF = ws_pfb + (size_t)(bb * BT) * 232;
        for (int i = wv; i < 14; i += 4)
            dma16((const char*)srcF + i * 1024 + lane * 16, (char*)pfb_l + i * 1024);
        if (wv == 2 && lane < 32)      // tail: bytes 14336..14848
            dma16((const char*)srcF + 14 * 1024 + lane * 16, (char*)pfb_l + 14 * 1024);
    }

    // ---- phase-1 b-frags: direct global, depth-1 pipeline
    const unsigned short* pB0 = ws_pdt + ((size_t)vb * 192 + wv * 48 + r16) * 40 + half8;
    bf16x8 b0 = *(const bf16x8*)(pB0);
    bf16x8 b1 = *(const bf16x8*)(pB0 + 640);    // +16 rows * 40
    bf16x8 b2 = *(const bf16x8*)(pB0 + 1280);   // +32 rows * 40

    f32x4 acc[2][3];
    #pragma unroll
    for (int mt = 0; mt < 2; mt++)
        #pragma unroll
        for (int t = 0; t < 3; t++)
            acc[mt][t] = (f32x4){0.f, 0.f, 0.f, 0.f};

    __syncthreads();      // pfb DMA landed

    #pragma unroll
    for (int kc = 0; kc < NCHUNK; kc++) {
        // a-frags from LDS (2-way bank aliasing = free)
        bf16x8 a0 = *(const bf16x8*)(pfb_l + r16 * 232 + kc * 32 + half8);
        bf16x8 a1 = *(const bf16x8*)(pfb_l + (16 + r16) * 232 + kc * 32 + half8);
        bf16x8 b0n, b1n, b2n;
        if (kc < NCHUNK - 1) {
            const unsigned short* pn = pB0 + (size_t)(kc + 1) * NCOL * 40;
            b0n = *(const bf16x8*)(pn);
            b1n = *(const bf16x8*)(pn + 640);
            b2n = *(const bf16x8*)(pn + 1280);
        }
        acc[0][0] = __builtin_amdgcn_mfma_f32_16x16x32_bf16(a0, b0, acc[0][0], 0, 0, 0);
        acc[1][0] = __builtin_amdgcn_mfma_f32_16x16x32_bf16(a1, b0, acc[1][0], 0, 0, 0);
        acc[0][1] = __builtin_amdgcn_mfma_f32_16x16x32_bf16(a0, b1, acc[0][1], 0, 0, 0);
        acc[1][1] = __builtin_amdgcn_mfma_f32_16x16x32_bf16(a1, b1, acc[1][1], 0, 0, 0);
        acc[0][2] = __builtin_amdgcn_mfma_f32_16x16x32_bf16(a0, b2, acc[0][2], 0, 0, 0);
        acc[1][2] = __builtin_amdgcn_mfma_f32_16x16x32_bf16(a1, b2, acc[1][2], 0, 0, 0);
        if (kc < NCHUNK - 1) { b0 = b0n; b1 = b1n; b2 = b2n; }
    }

    // ---- scatter v_posed into disp_l (pfb_l region untouched -> no race)
    // stride 196: lane-groups land at bank offsets {0,16,0,16} -> 2-way (free)
    #pragma unroll
    for (int mt = 0; mt < 2; mt++) {
        #pragma unroll
        for (int t = 0; t < 3; t++) {
            int col = wv * 48 + t * 16 + r16;
            int brow = mt * 16 + (lane >> 4) * 4;
            #pragma unroll
            for (int r = 0; r < 4; r++)
                disp_l[(brow + r) * 196 + col] = acc[mt][t][r];
        }
    }
    __syncthreads();      // disp complete

    // ---- phase 2: wave wv owns subs {wv, wv+4}, all 4 vert-groups.
    // C[artcol][vert] = mfma(c_frag, aw[vg]); lane g=lane>>4 holds all 4
    // n-components of (batch bl, row mm) with q=4t+g in its 4 acc regs.
    const int gq = lane >> 4;
    int bl[3], mm[3];
    #pragma unroll
    for (int t = 0; t < 3; t++) {
        int q = 4 * t + gq;                   // 0..11
        bl[t] = (q * 11) >> 5;                // q/3 for q in [0,12)
        mm[t] = q - 3 * bl[t];
    }

    bf16x8 aw[4];
    #pragma unroll
    for (int vg = 0; vg < 4; vg++)
        aw[vg] = *(const bf16x8*)(ws_wb + (size_t)(vb * 64 + vg * 16 + r16) * 40 + half8);

    const unsigned short* pArt0 = ws_artb + (size_t)(bb * BT) * 480 + (size_t)r16 * 40 + half8;

    // prologue c-frags for sub = wv
    const unsigned short* pc = pArt0 + (size_t)wv * 1920;   // 4 batches * 480
    bf16x8 c0 = *(const bf16x8*)(pc);
    bf16x8 c1 = *(const bf16x8*)(pc + 640);
    bf16x8 c2 = *(const bf16x8*)(pc + 1280);

    #pragma unroll
    for (int h = 0; h < 2; h++) {
        const int sub = wv + h * 4;
        bf16x8 c0n, c1n, c2n;
        if (h == 0) {
            const unsigned short* pn = pArt0 + (size_t)(wv + 4) * 1920;
            c0n = *(const bf16x8*)(pn);
            c1n = *(const bf16x8*)(pn + 640);
            c2n = *(const bf16x8*)(pn + 1280);
        }
        #pragma unroll
        for (int vg = 0; vg < 4; vg++) {
            f32x4 z = (f32x4){0.f, 0.f, 0.f, 0.f};
            f32x4 t0 = __builtin_amdgcn_mfma_f32_16x16x32_bf16(c0, aw[vg], z, 0, 0, 0);
            f32x4 t1 = __builtin_amdgcn_mfma_f32_16x16x32_bf16(c1, aw[vg], z, 0, 0, 0);
            f32x4 t2 = __builtin_amdgcn_mfma_f32_16x16x32_bf16(c2, aw[vg], z, 0, 0, 0);

            const int v16 = vg * 16 + r16;           // vert within block
            const int vg_glob = vb * 64 + v16;       // global vert
            #pragma unroll
            for (int t = 0; t < 3; t++) {
                f32x4 tt = (t == 0) ? t0 : (t == 1) ? t1 : t2;
                int row = sub * 4 + bl[t];
                const float* d = disp_l + row * 196 + v16 * 3;
                float x = d[0], y = d[1], zz = d[2];
                float p = tt[0] * x + tt[1] * y + tt[2] * zz + tt[3];
                if (vg_glob < NV)
                    out[(size_t)(bb * BT + row) * N3 + (size_t)vg_glob * 3 + mm[t]] = p;
            }
        }
        if (h == 0) { c0 = c0n; c1 = c1n; c2 = c2n; }
    }
}

// ---------------------------------------------------------------------------
extern "C" void kernel_launch(void* const* d_in, const int* in_sizes, int n_in,
                              void* d_out, int out_size, void* d_ws, size_t ws_size,
                              hipStream_t stream) {
    const float* betas = (const float*)d_in[0];
    const float* grot  = (const float*)d_in[1];
    const float* bpose = (const float*)d_in[2];
    const float* vtm   = (const float*)d_in[3];
    const float* sd    = (const float*)d_in[4];
    const float* pd    = (const float*)d_in[5];
    const float* Jr    = (const float*)d_in[6];
    const float* w     = (const float*)d_in[7];
    float* out = (float*)d_out;

    char* ws = (char*)d_ws;
    unsigned short* ws_pdt  = (unsigned short*)(ws);              // 11,612,160 B
    unsigned short* ws_pfb  = (unsigned short*)(ws + 11612160);   //    475,136 B
    unsigned short* ws_wb   = (unsigned short*)(ws + 12087296);   //    552,960 B
    float*          ws_jsp  = (float*)         (ws + 12640256);   //     25,344 B
    unsigned short* ws_artb = (unsigned short*)(ws + 12665600);   //    983,040 B

    k_prep<<<1645, 256, 0, stream>>>(pd, sd, vtm, Jr, bpose, betas, w,
                                     ws_pdt, ws_pfb, ws_wb, ws_jsp);
    k_chain<<<BN / 16, 256, 0, stream>>>(betas, grot, bpose, ws_jsp, ws_artb,
                                         out + (size_t)BN * N3);
    k_vert<<<dim3(32, 108), 256, 0, stream>>>(ws_pdt, ws_pfb, ws_wb, ws_artb, out);
}